// Round 1
// baseline (192.725 us; speedup 1.0000x reference)
//
#include <hip/hip_runtime.h>
#include <hip/hip_bf16.h>

// Problem constants (from reference): B=2, C=128, T=5 (Tc=4 ctx), H=W=48,
// heads h=64, PATCH=7 (pad 3), K = Tc*49 = 196 keys per pixel.
#define BATCH 2
#define CCH 128
#define TT 5
#define TC 4
#define HH 48
#define WW 48
#define HWPIX (HH*WW)          // 2304
#define NHEAD 64
#define PAD 3
#define NKEY 196               // 4*49

// ---------------------------------------------------------------------------
// K1: projections. For each (b,t) plane compute either theta (t==0) or
// phi & g (t>=1) for a 16-head group over 256 pixels per block.
// Output layout: h-contiguous per pixel so K2 can read float4s.
//   q_ws  [b][pix][64]
//   phi_ws[b][t-1][pix][64]
//   g_ws  [b][t-1][pix][64]
// ---------------------------------------------------------------------------
__global__ __launch_bounds__(256) void proj_kernel(
    const float* __restrict__ x,
    const float* __restrict__ w_theta,
    const float* __restrict__ w_phi,
    const float* __restrict__ w_g,
    float* __restrict__ q_ws,
    float* __restrict__ phi_ws,
    float* __restrict__ g_ws)
{
    const int tile = blockIdx.x;      // 0..8  (2304/256)
    const int hg   = blockIdx.y;      // 0..3  (head group of 16)
    const int bz   = blockIdx.z;      // 0..9  (b*5 + t)
    const int b = bz / TT;
    const int t = bz % TT;
    const int pix = tile * 256 + threadIdx.x;
    const int h0 = hg * 16;

    __shared__ float wA[16 * CCH];
    __shared__ float wB[16 * CCH];

    const float* wsrcA = (t == 0) ? w_theta : w_phi;
    for (int idx = threadIdx.x; idx < 16 * CCH; idx += 256) {
        wA[idx] = wsrcA[h0 * CCH + idx];
        wB[idx] = w_g[h0 * CCH + idx];
    }
    __syncthreads();

    float acc[16], accg[16];
#pragma unroll
    for (int j = 0; j < 16; ++j) { acc[j] = 0.f; accg[j] = 0.f; }

    const float* xp = x + (size_t)((b * CCH) * TT + t) * HWPIX + pix;
#pragma unroll 4
    for (int c = 0; c < CCH; ++c) {
        const float xv = xp[(size_t)c * (TT * HWPIX)];
#pragma unroll
        for (int j = 0; j < 16; ++j) {
            acc[j]  = fmaf(wA[j * CCH + c], xv, acc[j]);
            accg[j] = fmaf(wB[j * CCH + c], xv, accg[j]);
        }
    }

    if (t == 0) {
        float4* d4 = (float4*)(q_ws + (size_t)(b * HWPIX + pix) * NHEAD + h0);
#pragma unroll
        for (int j = 0; j < 4; ++j)
            d4[j] = make_float4(acc[4*j], acc[4*j+1], acc[4*j+2], acc[4*j+3]);
    } else {
        const size_t base = (size_t)((b * TC + (t - 1)) * HWPIX + pix) * NHEAD + h0;
        float4* dp = (float4*)(phi_ws + base);
        float4* dg = (float4*)(g_ws + base);
#pragma unroll
        for (int j = 0; j < 4; ++j) {
            dp[j] = make_float4(acc[4*j],  acc[4*j+1],  acc[4*j+2],  acc[4*j+3]);
            dg[j] = make_float4(accg[4*j], accg[4*j+1], accg[4*j+2], accg[4*j+3]);
        }
    }
}

// ---------------------------------------------------------------------------
// K2: per-pixel attention + output projection + residual.
// One 256-thread block per pixel (grid = B*H*W = 4608).
// ---------------------------------------------------------------------------
__global__ __launch_bounds__(256) void attn_kernel(
    const float* __restrict__ x,
    const float* __restrict__ w_out,
    const float* __restrict__ q_ws,
    const float* __restrict__ phi_ws,
    const float* __restrict__ g_ws,
    float* __restrict__ out)
{
    const int p   = blockIdx.x;             // 0..4607
    const int b   = p / HWPIX;
    const int rem = p % HWPIX;
    const int X   = rem / WW;               // H index
    const int Y   = rem % WW;               // W index
    const int tid = threadIdx.x;

    __shared__ __align__(16) float q_s[NHEAD];
    __shared__ float red[256];
    __shared__ float att_s[NKEY];
    __shared__ float ypart[4][NHEAD];
    __shared__ __align__(16) float y_s[NHEAD];

    if (tid < NHEAD) q_s[tid] = q_ws[(size_t)p * NHEAD + tid];
    __syncthreads();

    // ---- phase 1: scores (thread k -> key k) ----
    float sc = -1e30f;
    if (tid < NKEY) {
        const int t_ = tid / 49;
        const int r  = tid % 49;
        const int i  = r / 7;
        const int j  = r % 7;
        const int nx = min(max(X - PAD + i, 0), HH - 1);
        const int ny = min(max(Y - PAD + j, 0), WW - 1);
        const float4* ph4 =
            (const float4*)(phi_ws + (size_t)((b * TC + t_) * HWPIX + nx * WW + ny) * NHEAD);
        const float4* q4 = (const float4*)q_s;
        float s = 0.f;
#pragma unroll
        for (int hh = 0; hh < NHEAD / 4; ++hh) {
            const float4 a  = ph4[hh];
            const float4 qq = q4[hh];
            s += a.x * qq.x + a.y * qq.y + a.z * qq.z + a.w * qq.w;
        }
        sc = s * 8.0f;   // * sqrt(64)
    }

    // ---- softmax over 196 (padded to 256) ----
    red[tid] = sc;
    __syncthreads();
    for (int off = 128; off > 0; off >>= 1) {
        if (tid < off) red[tid] = fmaxf(red[tid], red[tid + off]);
        __syncthreads();
    }
    const float m = red[0];
    __syncthreads();
    const float e = (tid < NKEY) ? __expf(sc - m) : 0.f;
    red[tid] = e;
    __syncthreads();
    for (int off = 128; off > 0; off >>= 1) {
        if (tid < off) red[tid] += red[tid + off];
        __syncthreads();
    }
    const float inv = 1.0f / red[0];
    if (tid < NKEY) att_s[tid] = e * inv;
    __syncthreads();

    // ---- phase 2: y[h] = sum_k att[k] * g[key_k][h] ----
    {
        const int w  = tid >> 6;    // wave 0..3
        const int hh = tid & 63;
        float acc = 0.f;
        for (int k = w; k < NKEY; k += 4) {
            const int t2 = k / 49;
            const int r2 = k % 49;
            const int i2 = r2 / 7;
            const int j2 = r2 % 7;
            const int nx = min(max(X - PAD + i2, 0), HH - 1);
            const int ny = min(max(Y - PAD + j2, 0), WW - 1);
            acc = fmaf(att_s[k],
                       g_ws[(size_t)((b * TC + t2) * HWPIX + nx * WW + ny) * NHEAD + hh],
                       acc);
        }
        ypart[w][hh] = acc;
    }
    __syncthreads();
    if (tid < NHEAD)
        y_s[tid] = ypart[0][tid] + ypart[1][tid] + ypart[2][tid] + ypart[3][tid];
    __syncthreads();

    // ---- phase 3: z[c] = x[b,c,0,X,Y] + sum_h y[h] * w_out[c,h] ----
    if (tid < CCH) {
        const int c = tid;
        const float4* w4 = (const float4*)(w_out + (size_t)c * NHEAD);
        const float4* y4 = (const float4*)y_s;
        float s = 0.f;
#pragma unroll
        for (int qq = 0; qq < NHEAD / 4; ++qq) {
            const float4 a = w4[qq];
            const float4 y = y4[qq];
            s += a.x * y.x + a.y * y.y + a.z * y.z + a.w * y.w;
        }
        const float xi = x[(((size_t)(b * CCH + c) * TT) * HH + X) * WW + Y];
        out[((size_t)(b * CCH + c) * HH + X) * WW + Y] = xi + s;
    }
}

// ---------------------------------------------------------------------------
extern "C" void kernel_launch(void* const* d_in, const int* in_sizes, int n_in,
                              void* d_out, int out_size, void* d_ws, size_t ws_size,
                              hipStream_t stream)
{
    const float* x       = (const float*)d_in[0];
    const float* w_theta = (const float*)d_in[1];
    const float* w_phi   = (const float*)d_in[2];
    const float* w_g     = (const float*)d_in[3];
    const float* w_out   = (const float*)d_in[4];
    float* out = (float*)d_out;

    float* ws     = (float*)d_ws;
    float* q_ws   = ws;                                    // B*HW*64      = 294912
    float* phi_ws = q_ws + (size_t)BATCH * HWPIX * NHEAD;  // B*Tc*HW*64   = 1179648
    float* g_ws   = phi_ws + (size_t)BATCH * TC * HWPIX * NHEAD;

    dim3 g1(HWPIX / 256, 4, BATCH * TT);   // (9, 4, 10)
    proj_kernel<<<g1, 256, 0, stream>>>(x, w_theta, w_phi, w_g, q_ws, phi_ws, g_ws);

    attn_kernel<<<BATCH * HWPIX, 256, 0, stream>>>(x, w_out, q_ws, phi_ws, g_ws, out);
}

// Round 2
// 180.304 us; speedup vs baseline: 1.0689x; 1.0689x over previous
//
#include <hip/hip_runtime.h>
#include <hip/hip_bf16.h>
#include <math.h>

// B=2, C=128, T=5 (Tc=4 ctx), H=W=48, heads=64, PATCH=7 (pad 3), K=196.
#define BATCH 2
#define CCH 128
#define TT 5
#define TC 4
#define HH 48
#define WW 48
#define HWPIX 2304
#define NHEAD 64
#define PAD 3
#define NKEY 196
#define XSTRIDE (TT*HWPIX)   // per-channel stride in x

// ---------------------------------------------------------------------------
// K1: projections. Weights read via wave-uniform (scalar) loads — no LDS.
// grid = (9 pixtiles, 4 headgroups, 20 = (b*5+t)*2 + sel)
//   sel 0: theta (t==0) or phi (t>0);  sel 1: g (t>0 only)
// Each thread: 1 pixel x 16 heads, 128-c dot, pure v_fmac with SGPR weights.
// Output h-contiguous: q_ws[b][pix][64], phi_ws/g_ws[b][t-1][pix][64].
// ---------------------------------------------------------------------------
__global__ __launch_bounds__(256) void proj_kernel(
    const float* __restrict__ x,
    const float* __restrict__ w_theta,
    const float* __restrict__ w_phi,
    const float* __restrict__ w_g,
    float* __restrict__ q_ws,
    float* __restrict__ phi_ws,
    float* __restrict__ g_ws)
{
    const int z   = blockIdx.z;
    const int bt  = z >> 1;
    const int sel = z & 1;
    const int b = bt / TT;
    const int t = bt % TT;
    if (t == 0 && sel == 1) return;   // only theta on frame 0

    const int pix = blockIdx.x * 256 + threadIdx.x;
    const int h0  = blockIdx.y * 16;

    const float* w  = (sel == 0) ? ((t == 0) ? w_theta : w_phi) : w_g;
    const float* wp = w + (size_t)h0 * CCH;
    const float* xp = x + ((size_t)(b * CCH) * TT + t) * HWPIX + pix;

    float acc[16];
#pragma unroll
    for (int j = 0; j < 16; ++j) acc[j] = 0.f;

    for (int c = 0; c < CCH; c += 4) {
        float xv0 = xp[(size_t)(c + 0) * XSTRIDE];
        float xv1 = xp[(size_t)(c + 1) * XSTRIDE];
        float xv2 = xp[(size_t)(c + 2) * XSTRIDE];
        float xv3 = xp[(size_t)(c + 3) * XSTRIDE];
#pragma unroll
        for (int j = 0; j < 16; ++j) {
            // wave-uniform addresses -> s_load_dwordx4 per (j, c-chunk)
            acc[j] = fmaf(wp[j * CCH + c + 0], xv0, acc[j]);
            acc[j] = fmaf(wp[j * CCH + c + 1], xv1, acc[j]);
            acc[j] = fmaf(wp[j * CCH + c + 2], xv2, acc[j]);
            acc[j] = fmaf(wp[j * CCH + c + 3], xv3, acc[j]);
        }
    }

    float* dst;
    if (t == 0) {
        dst = q_ws + (size_t)(b * HWPIX + pix) * NHEAD + h0;
    } else {
        float* base = sel ? g_ws : phi_ws;
        dst = base + (size_t)((b * TC + (t - 1)) * HWPIX + pix) * NHEAD + h0;
    }
    float4* d4 = (float4*)dst;
#pragma unroll
    for (int j = 0; j < 4; ++j)
        d4[j] = make_float4(acc[4*j], acc[4*j+1], acc[4*j+2], acc[4*j+3]);
}

// ---------------------------------------------------------------------------
// K2: wave-per-pixel attention. 4 pixels per 256-thread block.
// Phase 1: lane l scores keys l, l+64, l+128 (+192 for lanes 0-3); offsets
// cached. Softmax via __shfl_xor (no barriers). Phase 2: lane h accumulates
// y[h] over 196 keys using LDS-cached (att, offset); g loads coalesced on h.
// Writes y_ws[p][64] (aliases q_ws — q read before y written, same wave).
// ---------------------------------------------------------------------------
__global__ __launch_bounds__(256) void attn_kernel(
    const float* __restrict__ phi_ws,
    const float* __restrict__ g_ws,
    const float* q_ws,        // no restrict: aliases y_ws
    float*       y_ws)
{
    __shared__ float att_s[4][208];
    __shared__ int   off_s[4][208];

    const int w    = threadIdx.x >> 6;
    const int lane = threadIdx.x & 63;
    const int p    = blockIdx.x * 4 + w;
    const int b    = p / HWPIX;
    const int rem  = p % HWPIX;
    const int X    = rem / WW;
    const int Y    = rem % WW;

    // q for this pixel: wave-uniform loads
    float4 qr[16];
    const float4* q4 = (const float4*)(q_ws + (size_t)p * NHEAD);
#pragma unroll
    for (int i = 0; i < 16; ++i) qr[i] = q4[i];

    float sc[4];
#pragma unroll
    for (int s = 0; s < 4; ++s) {
        const int k = lane + 64 * s;
        const bool valid = (s < 3) || (lane < 4);
        float d = -INFINITY;
        if (valid) {
            const int t_ = k / 49;
            const int r  = k % 49;
            const int i  = r / 7;
            const int j  = r % 7;
            const int nx = min(max(X - PAD + i, 0), HH - 1);
            const int ny = min(max(Y - PAD + j, 0), WW - 1);
            const int o  = ((b * TC + t_) * HWPIX + nx * WW + ny) * NHEAD;
            off_s[w][k] = o;
            const float4* ph = (const float4*)(phi_ws + o);
            float s0 = 0.f;
#pragma unroll
            for (int hh = 0; hh < 16; ++hh) {
                const float4 a = ph[hh];
                const float4 q = qr[hh];
                s0 += a.x*q.x + a.y*q.y + a.z*q.z + a.w*q.w;
            }
            d = s0 * 8.0f;   // * sqrt(64)
        }
        sc[s] = d;
    }

    // wave softmax over 196 (lanes' 3-4 local scores)
    float m = fmaxf(fmaxf(sc[0], sc[1]), fmaxf(sc[2], sc[3]));
#pragma unroll
    for (int d = 32; d > 0; d >>= 1) m = fmaxf(m, __shfl_xor(m, d));

    float e[4], sum = 0.f;
#pragma unroll
    for (int s = 0; s < 4; ++s) { e[s] = __expf(sc[s] - m); sum += e[s]; }
#pragma unroll
    for (int d = 32; d > 0; d >>= 1) sum += __shfl_xor(sum, d);
    const float inv = 1.0f / sum;

    att_s[w][lane]       = e[0] * inv;
    att_s[w][64 + lane]  = e[1] * inv;
    att_s[w][128 + lane] = e[2] * inv;
    if (lane < 4) att_s[w][192 + lane] = e[3] * inv;

    __threadfence_block();   // drain LDS writes (per-wave visibility)

    // phase 2: y[lane] = sum_k att[k] * g[key_k][lane]
    float acc = 0.f;
    for (int kb = 0; kb < 49; ++kb) {
        const float4 a = *(const float4*)&att_s[w][kb * 4];
        const int4   o = *(const int4*)&off_s[w][kb * 4];
        acc = fmaf(a.x, g_ws[(size_t)o.x + lane], acc);
        acc = fmaf(a.y, g_ws[(size_t)o.y + lane], acc);
        acc = fmaf(a.z, g_ws[(size_t)o.z + lane], acc);
        acc = fmaf(a.w, g_ws[(size_t)o.w + lane], acc);
    }
    y_ws[(size_t)p * NHEAD + lane] = acc;
}

// ---------------------------------------------------------------------------
// K3: output projection + residual, fully coalesced on pixels.
// grid = (18 pixtiles, 16 c-groups of 8). w_out via wave-uniform scalar loads.
// ---------------------------------------------------------------------------
__global__ __launch_bounds__(256) void out_kernel(
    const float* __restrict__ x,
    const float* __restrict__ w_out,
    const float* __restrict__ y_ws,
    float* __restrict__ out)
{
    const int p   = blockIdx.x * 256 + threadIdx.x;  // 0..4607
    const int c0  = blockIdx.y * 8;
    const int b   = p / HWPIX;
    const int rem = p % HWPIX;

    float4 yr[16];
    const float4* y4 = (const float4*)(y_ws + (size_t)p * NHEAD);
#pragma unroll
    for (int i = 0; i < 16; ++i) yr[i] = y4[i];

    float acc[8];
#pragma unroll
    for (int j = 0; j < 8; ++j) acc[j] = 0.f;

#pragma unroll
    for (int hh = 0; hh < 16; ++hh) {
        const float4 yv = yr[hh];
#pragma unroll
        for (int j = 0; j < 8; ++j) {
            const float4 wv = *(const float4*)(w_out + (size_t)(c0 + j) * NHEAD + hh * 4);
            acc[j] += wv.x*yv.x + wv.y*yv.y + wv.z*yv.z + wv.w*yv.w;
        }
    }

#pragma unroll
    for (int j = 0; j < 8; ++j) {
        const int c = c0 + j;
        const float xi = x[((size_t)(b * CCH + c) * TT) * HWPIX + rem];
        out[(size_t)(b * CCH + c) * HWPIX + rem] = xi + acc[j];
    }
}

// ---------------------------------------------------------------------------
extern "C" void kernel_launch(void* const* d_in, const int* in_sizes, int n_in,
                              void* d_out, int out_size, void* d_ws, size_t ws_size,
                              hipStream_t stream)
{
    const float* x       = (const float*)d_in[0];
    const float* w_theta = (const float*)d_in[1];
    const float* w_phi   = (const float*)d_in[2];
    const float* w_g     = (const float*)d_in[3];
    const float* w_out   = (const float*)d_in[4];
    float* out = (float*)d_out;

    float* ws     = (float*)d_ws;
    float* q_ws   = ws;                                        // B*HW*64
    float* phi_ws = q_ws + (size_t)BATCH * HWPIX * NHEAD;      // B*Tc*HW*64
    float* g_ws   = phi_ws + (size_t)BATCH * TC * HWPIX * NHEAD;
    float* y_ws   = q_ws;   // alias: q consumed before y written (same wave)

    dim3 g1(HWPIX / 256, 4, BATCH * TT * 2);   // (9, 4, 20)
    proj_kernel<<<g1, 256, 0, stream>>>(x, w_theta, w_phi, w_g, q_ws, phi_ws, g_ws);

    attn_kernel<<<BATCH * HWPIX / 4, 256, 0, stream>>>(phi_ws, g_ws, q_ws, y_ws);

    dim3 g3(BATCH * HWPIX / 256, CCH / 8);     // (18, 16)
    out_kernel<<<g3, 256, 0, stream>>>(x, w_out, y_ws, out);
}